// Round 5
// baseline (644.534 us; speedup 1.0000x reference)
//
#include <hip/hip_runtime.h>
#include <hip/hip_bf16.h>

typedef __hip_bfloat16 bf16;
typedef unsigned short ushort_t;
typedef float f32x4 __attribute__((ext_vector_type(4)));
typedef short bf16x8 __attribute__((ext_vector_type(8)));
typedef ushort_t u16x4 __attribute__((ext_vector_type(4)));

#define MFMA16(a, b, c) __builtin_amdgcn_mfma_f32_16x16x32_bf16(a, b, c, 0, 0, 0)

__device__ inline ushort_t f2b(float f) {
  bf16 h = __float2bfloat16(f);
  return __builtin_bit_cast(ushort_t, h);
}
__device__ inline float b2f(ushort_t u) {
  bf16 h = __builtin_bit_cast(bf16, u);
  return __bfloat162float(h);
}
// bf16 pair unpack (bf16 -> f32 is a 16-bit shift)
__device__ inline float blo(unsigned d) { return __builtin_bit_cast(float, d << 16); }
__device__ inline float bhi(unsigned d) { return __builtin_bit_cast(float, d & 0xffff0000u); }

// Geometry: B=16, C=128, H=W=128, HW=16384, S1=S2=64
// h buffer (bf16) layout: (B, 256, HW); ch 0..63 = a1, 64..127 = a2, 128..255 = xh
// MFMA frag layouts (16x16x32 bf16, m89/m91-verified):
//   A: lane l holds A[m = l&15][k = (l>>4)*8 + j], j=0..7
//   B: lane l holds W[n = l&15][k = (l>>4)*8 + j]  (B^T-input convention)
//   D: lane l reg r holds D[m = (l>>4)*4 + r][n = l&15]

// ---------------------------------------------------------------------------
// Weight pre-pack kernels (bf16, B-fragment order).
// ---------------------------------------------------------------------------
__global__ __launch_bounds__(256) void prepack_pf(
    const float* __restrict__ pf_w, ushort_t* __restrict__ pf_wp)
{
  int idx = blockIdx.x * 256 + threadIdx.x;  // 32768 = 16 tiles * 4 kc * 64 * 8
  int j = idx & 7, lane = (idx >> 3) & 63, kc = (idx >> 9) & 3, t = idx >> 11;
  int oc = t * 16 + (lane & 15), ic = kc * 32 + (lane >> 4) * 8 + j;
  pf_wp[idx] = f2b(pf_w[oc * 128 + ic]);
}

__global__ __launch_bounds__(256) void prepack_small(
    const float* __restrict__ w4, const float* __restrict__ w5,
    const float* __restrict__ plw, ushort_t* __restrict__ dst)
{
  int idx = blockIdx.x * 256 + threadIdx.x;  // 24576: [0,4096) w4p, [4096,8192) w5p, rest plwp
  if (idx < 8192) {
    const float* src = (idx < 4096) ? w4 : w5;
    int k = idx & 4095;
    int j = k & 7, lane = (k >> 3) & 63, kc = (k >> 9) & 1, t = k >> 10;
    int oc = t * 16 + (lane & 15), ic = kc * 32 + (lane >> 4) * 8 + j;
    dst[idx] = f2b(src[oc * 64 + ic]);
  } else {
    int k = idx - 8192;  // 16384 = 8 tiles * 4 kc * 64 * 8
    int j = k & 7, lane = (k >> 3) & 63, kc = (k >> 9) & 3, t = k >> 11;
    int oc = t * 16 + (lane & 15), ic = kc * 32 + (lane >> 4) * 8 + j;
    dst[idx] = f2b(plw[oc * 128 + ic]);
  }
}

// ---------------------------------------------------------------------------
// K1: fused LayerNorm + pointwise 128->256 via bf16 MFMA. Block = 64 px.
// ---------------------------------------------------------------------------
__global__ __launch_bounds__(256) void ln_pf_mfma(
    const float* __restrict__ x, const float* __restrict__ ln_w,
    const float* __restrict__ ln_b, const ushort_t* __restrict__ pf_wp,
    const float* __restrict__ pf_b, ushort_t* __restrict__ h)
{
  __shared__ __attribute__((aligned(16))) unsigned char sm[34816];
  ushort_t* xs = (ushort_t*)sm;             // [64 px][136] bf16 (A-layout, pad 8)
  float* red = (float*)(sm + 17408);        // partial sums [2][4][64]
  float* mrs = (float*)(sm + 17408 + 2048); // mean[64], rstd[64]

  const int tid = threadIdx.x;
  const int p = tid & 63, cg = tid >> 6;
  const int g0 = blockIdx.x * 64;
  const int b = g0 >> 14, hw0 = g0 & 16383;
  const float* xp = x + (long)b * (128L * 16384) + hw0 + p;

  float v[32];
  #pragma unroll
  for (int i = 0; i < 32; ++i) v[i] = xp[(long)(cg * 32 + i) * 16384];
  float s = 0.f, ss = 0.f;
  #pragma unroll
  for (int i = 0; i < 32; ++i) { s += v[i]; ss += v[i] * v[i]; }
  red[cg * 64 + p] = s;
  red[256 + cg * 64 + p] = ss;
  __syncthreads();
  if (tid < 64) {
    float st = red[tid] + red[64 + tid] + red[128 + tid] + red[192 + tid];
    float sst = red[256 + tid] + red[320 + tid] + red[384 + tid] + red[448 + tid];
    float m = st * 0.0078125f;
    float var = sst * 0.0078125f - m * m;
    mrs[tid] = m;
    mrs[64 + tid] = rsqrtf(var + 1e-6f);
  }
  __syncthreads();
  {
    float m = mrs[p], rs = mrs[64 + p];
    #pragma unroll
    for (int i = 0; i < 32; ++i) {
      int c = cg * 32 + i;
      xs[p * 136 + c] = f2b((v[i] - m) * rs * ln_w[c] + ln_b[c]);
    }
  }
  __syncthreads();

  const int l = tid & 63, lm = l & 15, q = l >> 4;
  const int wv = __builtin_amdgcn_readfirstlane(tid >> 6);
  f32x4 acc[4][4];
  #pragma unroll
  for (int a = 0; a < 4; ++a)
    #pragma unroll
    for (int n = 0; n < 4; ++n) acc[a][n] = {0.f, 0.f, 0.f, 0.f};

  #pragma unroll
  for (int kc = 0; kc < 4; ++kc) {
    bf16x8 af[4], bfr[4];
    #pragma unroll
    for (int mt = 0; mt < 4; ++mt)
      af[mt] = *(const bf16x8*)&xs[(mt * 16 + lm) * 136 + kc * 32 + q * 8];
    #pragma unroll
    for (int nt = 0; nt < 4; ++nt)
      bfr[nt] = *(const bf16x8*)&pf_wp[(((wv * 4 + nt) * 4 + kc) * 64 + l) * 8];
    #pragma unroll
    for (int mt = 0; mt < 4; ++mt)
      #pragma unroll
      for (int nt = 0; nt < 4; ++nt)
        acc[mt][nt] = MFMA16(af[mt], bfr[nt], acc[mt][nt]);
  }
  __syncthreads();

  // epilogue: + bias, transpose via LDS to [oc][px], then coalesced store
  ushort_t* hst = (ushort_t*)sm;  // [256 oc][68 px] bf16
  #pragma unroll
  for (int nt = 0; nt < 4; ++nt) {
    int oc = wv * 64 + nt * 16 + lm;
    float bias = pf_b[oc];
    #pragma unroll
    for (int mt = 0; mt < 4; ++mt) {
      int px0 = mt * 16 + q * 4;
      union { ushort_t u[4]; uint2 w; } pk;
      #pragma unroll
      for (int r = 0; r < 4; ++r) pk.u[r] = f2b(acc[mt][nt][r] + bias);
      *(uint2*)&hst[oc * 68 + px0] = pk.w;
    }
  }
  __syncthreads();
  {
    int px = (tid & 31) * 2;
    int ocb = tid >> 5;
    ushort_t* hp = h + (long)b * 256 * 16384 + hw0 + px;
    #pragma unroll
    for (int i = 0; i < 32; ++i) {
      int oc = ocb + 8 * i;
      *(unsigned*)(hp + (long)oc * 16384) = *(unsigned*)&hst[oc * 68 + px];
    }
  }
}

// ---------------------------------------------------------------------------
// Fused branch-1 depthwise chain (validated round 3).
// ---------------------------------------------------------------------------
__global__ __launch_bounds__(256) void dw_branch1_kernel(
    const bf16* __restrict__ hbuf,
    const float* __restrict__ w1, const float* __restrict__ b1,
    const float* __restrict__ w2, const float* __restrict__ b2,
    const float* __restrict__ w3, const float* __restrict__ b3,
    const float* __restrict__ wa, const float* __restrict__ ba,
    const float* __restrict__ wb, const float* __restrict__ bb,
    bf16* __restrict__ d3, bf16* __restrict__ x3o)
{
  __shared__ __attribute__((aligned(16))) unsigned char smem[28000];
  float* st1 = (float*)smem;                 // 26*140*4 = 14560 B
  float* st2 = (float*)(smem + 14560);       // 24*140*4 = 13440 B (post-sync)
  ushort_t* sa = (ushort_t*)(smem + 14560);  // 26*160*2 =  8320 B (pre-sync, overlays st2)
  unsigned* sad = (unsigned*)sa;

  const int t = blockIdx.x;
  const int band = t & 7, c = (t >> 3) & 63, b = t >> 9;
  const int y0 = band * 16;
  const int tid = threadIdx.x;
  const bf16* ap = hbuf + ((long)b * 256 + c) * 16384;

  // ---- zero pad columns (dwords 0..3 = cols 0..7, 68..79 = cols 136..159)
  for (int i = tid; i < 26 * 16; i += 256) {
    int r = i >> 4, j = i & 15;
    int dw = (j < 4) ? j : (64 + j);
    sad[r * 80 + dw] = 0u;
  }
  // ---- load 26 rows (gy = y0-5 .. y0+20), 128 cols as 64 dwords, coalesced
  {
    const int lane = tid & 63, w = tid >> 6;
    #pragma unroll
    for (int i = 0; i < 7; ++i) {
      int rr = w + 4 * i;
      if (rr < 26) {
        int gy = y0 - 5 + rr;
        unsigned val = 0u;
        if ((unsigned)gy < 128u) val = *(const unsigned*)(ap + gy * 128 + lane * 2);
        sad[rr * 80 + 4 + lane] = val;
      }
    }
  }
  __syncthreads();

  // ---- stage B: st1 = conv1x3 horiz (w1), 26 rows x 136 cols, 8-col tasks
  {
    float W0 = w1[c * 3], Wm = w1[c * 3 + 1], Wp = w1[c * 3 + 2];
    const float B1v = b1[c];
    for (int task = tid; task < 26 * 17; task += 256) {
      int r = task / 17, g = task - r * 17;
      int c0 = g * 8;  // st1 cols c0..c0+7, x = c0-4..c0+3
      const unsigned* sr = sad + r * 80 + (c0 >> 1) + 1;
      unsigned e0 = sr[0], e1 = sr[1], e2 = sr[2], e3 = sr[3], e4 = sr[4], e5 = sr[5];
      float vw[12];
      vw[0] = blo(e0); vw[1] = bhi(e0); vw[2] = blo(e1); vw[3] = bhi(e1);
      vw[4] = blo(e2); vw[5] = bhi(e2); vw[6] = blo(e3); vw[7] = bhi(e3);
      vw[8] = blo(e4); vw[9] = bhi(e4); vw[10] = blo(e5); vw[11] = bhi(e5);
      int gy = y0 - 5 + r;
      bool rok = (unsigned)gy < 128u;
      float* dst = &st1[r * 140 + c0];
      #pragma unroll
      for (int j = 0; j < 8; ++j) {
        float v = W0 * vw[j + 1] + Wm * vw[j + 2] + Wp * vw[j + 3] + B1v;
        int xx = c0 - 4 + j;
        dst[j] = (rok && (unsigned)xx < 128u) ? v : 0.f;
      }
    }
  }

  // thread -> output strip mapping: 16 col-groups x 16 rows
  const int tx = tid & 15, ty = tid >> 4;
  const int x0 = tx * 8;
  const int y = y0 + ty;

  // ---- stage E: x3o = (3x1 vert wb) o (1x3 horiz wa), direct from sa registers
  {
    float A0 = wa[c * 3], A1 = wa[c * 3 + 1], A2 = wa[c * 3 + 2];
    float Bv0 = wb[c * 3], Bv1 = wb[c * 3 + 1], Bv2 = wb[c * 3 + 2];
    const float BAv = ba[c], BBv = bb[c];
    float su[3][8];
    #pragma unroll
    for (int dy = 0; dy < 3; ++dy) {
      int gy2 = y - 1 + dy;
      int srow = ty + 4 + dy;  // gy2 - (y0-5)
      const unsigned* sr = sad + srow * 80 + (x0 >> 1) + 3;  // cols x0+6..x0+17
      unsigned e0 = sr[0], e1 = sr[1], e2 = sr[2], e3 = sr[3], e4 = sr[4], e5 = sr[5];
      float vw[12];
      vw[0] = blo(e0); vw[1] = bhi(e0); vw[2] = blo(e1); vw[3] = bhi(e1);
      vw[4] = blo(e2); vw[5] = bhi(e2); vw[6] = blo(e3); vw[7] = bhi(e3);
      vw[8] = blo(e4); vw[9] = bhi(e4); vw[10] = blo(e5); vw[11] = bhi(e5);
      bool rok = (unsigned)gy2 < 128u;
      #pragma unroll
      for (int j = 0; j < 8; ++j) {
        float v = A0 * vw[j + 1] + A1 * vw[j + 2] + A2 * vw[j + 3] + BAv;
        su[dy][j] = rok ? v : 0.f;
      }
    }
    union { ushort_t u[8]; uint4 v; } pk;
    #pragma unroll
    for (int j = 0; j < 8; ++j)
      pk.u[j] = f2b(Bv0 * su[0][j] + Bv1 * su[1][j] + Bv2 * su[2][j] + BBv);
    bf16* x3p = x3o + ((long)b * 64 + c) * 16384;
    *(uint4*)(x3p + y * 128 + x0) = pk.v;
  }
  __syncthreads();  // sa dead from here; st2 may overwrite its space

  // ---- stage C: st2 = conv3x1 vert (w2) over st1, 24 rows x 136 cols
  {
    float W0 = w2[c * 3], Wm = w2[c * 3 + 1], Wp = w2[c * 3 + 2];
    const float B2v = b2[c];
    for (int task = tid; task < 24 * 17; task += 256) {
      int q = task / 17, g = task - q * 17;
      int c0 = g * 8;
      const float* r0 = &st1[q * 140 + c0];
      const float* r1 = &st1[(q + 1) * 140 + c0];
      const float* r2 = &st1[(q + 2) * 140 + c0];
      int gy = y0 - 4 + q;
      bool rok = (unsigned)gy < 128u;
      float* dst = &st2[q * 140 + c0];
      #pragma unroll
      for (int j = 0; j < 8; ++j) {
        float v = W0 * r0[j] + Wm * r1[j] + Wp * r2[j] + B2v;
        int xx = c0 - 4 + j;
        dst[j] = (rok && (unsigned)xx < 128u) ? v : 0.f;
      }
    }
  }
  __syncthreads();

  // ---- stage D: d3 = dilated 5x5 (w3, dil 2) over st2
  {
    float W[25];
    #pragma unroll
    for (int k = 0; k < 25; ++k) W[k] = w3[c * 25 + k];
    float acc[8];
    #pragma unroll
    for (int j = 0; j < 8; ++j) acc[j] = b3[c];
    #pragma unroll
    for (int u = 0; u < 5; ++u) {
      const float* svr = &st2[(ty + 2 * u) * 140 + x0];  // cols x0 .. x0+15
      float vw[16];
      #pragma unroll
      for (int k = 0; k < 16; ++k) vw[k] = svr[k];
      #pragma unroll
      for (int vv = 0; vv < 5; ++vv)
        #pragma unroll
        for (int j = 0; j < 8; ++j)
          acc[j] += W[u * 5 + vv] * vw[j + 2 * vv];
    }
    union { ushort_t u[8]; uint4 v; } pk;
    #pragma unroll
    for (int j = 0; j < 8; ++j) pk.u[j] = f2b(acc[j]);
    bf16* d3p = d3 + ((long)b * 64 + c) * 16384;
    *(uint4*)(d3p + y * 128 + x0) = pk.v;
  }
}

// ---------------------------------------------------------------------------
// Fused branch-2 depthwise chain (validated in round 2).
// ---------------------------------------------------------------------------
__global__ __launch_bounds__(256) void dw_branch2_kernel(
    const bf16* __restrict__ hbuf,
    const float* __restrict__ w1, const float* __restrict__ b1,
    const float* __restrict__ w2, const float* __restrict__ b2,
    const float* __restrict__ w5, const float* __restrict__ b5,
    bf16* __restrict__ d5, bf16* __restrict__ x5o)
{
  __shared__ ushort_t sa[32 * 160];   // 10240 B
  __shared__ float sv[28 * 148];      // 16576 B

  const int t = blockIdx.x;
  const int band = t & 7, c = (t >> 3) & 63, b = t >> 9;
  const int y0 = band * 16;
  const int tid = threadIdx.x;
  const bf16* ap = hbuf + ((long)b * 256 + 64 + c) * 16384;

  // ---- zero the pad columns (dwords 0..3 = cols 0..7, 68..79 = cols 136..159)
  unsigned* sad = (unsigned*)sa;
  for (int i = tid; i < 32 * 16; i += 256) {
    int r = i >> 4, j = i & 15;
    int dw = (j < 4) ? j : (64 + j);
    sad[r * 80 + dw] = 0u;
  }
  // ---- load 32 rows (gy = y0-8 .. y0+23), 128 cols as 64 dwords, coalesced
  {
    const int lane = tid & 63, w = tid >> 6;
    #pragma unroll
    for (int i = 0; i < 8; ++i) {
      int rr = w + 4 * i;
      int gy = y0 - 8 + rr;
      unsigned val = 0u;
      if ((unsigned)gy < 128u) val = *(const unsigned*)(ap + gy * 128 + lane * 2);
      sad[rr * 80 + 4 + lane] = val;
    }
  }
  __syncthreads();

  // ---- stage 1: sv = conv5x5(sa) (w1), 28 rows x 144 cols, 8-col tasks
  {
    float W[25];
    #pragma unroll
    for (int k = 0; k < 25; ++k) W[k] = w1[c * 25 + k];
    const float B1v = b1[c];
    for (int task = tid; task < 28 * 18; task += 256) {
      int r = task / 18, g = task - r * 18;
      int c0 = g * 8;
      float acc[8];
      #pragma unroll
      for (int j = 0; j < 8; ++j) acc[j] = B1v;
      #pragma unroll
      for (int u = 0; u < 5; ++u) {
        const unsigned* sr = sad + (r + u) * 80 + (c0 >> 1);
        unsigned e0 = sr[0], e1 = sr[1], e2 = sr[2], e3 = sr[3], e4 = sr[4], e5 = sr[5];
        float vw[12];
        vw[0] = blo(e0); vw[1] = bhi(e0); vw[2] = blo(e1); vw[3] = bhi(e1);
        vw[4] = blo(e2); vw[5] = bhi(e2); vw[6] = blo(e3); vw[7] = bhi(e3);
        vw[8] = blo(e4); vw[9] = bhi(e4); vw[10] = blo(e5); vw[11] = bhi(e5);
        #pragma unroll
        for (int v5 = 0; v5 < 5; ++v5)
          #pragma unroll
          for (int j = 0; j < 8; ++j)
            acc[j] += W[u * 5 + v5] * vw[j + v5];
      }
      int gy = y0 - 6 + r;
      bool rok = (unsigned)gy < 128u;
      float* svr = &sv[r * 148 + c0];
      #pragma unroll
      for (int j = 0; j < 8; ++j) {
        int xx = c0 + j - 6;
        svr[j] = (rok && (unsigned)xx < 128u) ? acc[j] : 0.f;
      }
    }
  }

  // thread -> output mapping for stages 2/3: 16 col-groups x 16 rows
  const int tx = tid & 15, ty = tid >> 4;
  const int x0 = tx * 8;
  const int y = y0 + ty;

  // ---- stage 2: x5o = conv5x5(sa) (w5) at output rows (reads sa only)
  {
    float W[25];
    #pragma unroll
    for (int k = 0; k < 25; ++k) W[k] = w5[c * 25 + k];
    float acc[8];
    #pragma unroll
    for (int j = 0; j < 8; ++j) acc[j] = b5[c];
    #pragma unroll
    for (int u = 0; u < 5; ++u) {
      const unsigned* sr = sad + (ty + 6 + u) * 80 + (x0 >> 1);
      unsigned e0 = sr[3], e1 = sr[4], e2 = sr[5], e3 = sr[6], e4 = sr[7], e5 = sr[8];
      float vw[12];  // sa cols x0+6 .. x0+17
      vw[0] = blo(e0); vw[1] = bhi(e0); vw[2] = blo(e1); vw[3] = bhi(e1);
      vw[4] = blo(e2); vw[5] = bhi(e2); vw[6] = blo(e3); vw[7] = bhi(e3);
      vw[8] = blo(e4); vw[9] = bhi(e4); vw[10] = blo(e5); vw[11] = bhi(e5);
      #pragma unroll
      for (int v5 = 0; v5 < 5; ++v5)
        #pragma unroll
        for (int j = 0; j < 8; ++j)
          acc[j] += W[u * 5 + v5] * vw[j + v5];
    }
    union { ushort_t u[8]; uint4 v; } pk;
    #pragma unroll
    for (int j = 0; j < 8; ++j) pk.u[j] = f2b(acc[j]);
    bf16* x5p = x5o + ((long)b * 64 + c) * 16384;
    *(uint4*)(x5p + y * 128 + x0) = pk.v;
  }
  __syncthreads();

  // ---- stage 3: d5 = dilated 7x7 (w2, dil 2) over sv
  {
    float W[49];
    #pragma unroll
    for (int k = 0; k < 49; ++k) W[k] = w2[c * 49 + k];
    float acc[8];
    #pragma unroll
    for (int j = 0; j < 8; ++j) acc[j] = b2[c];
    #pragma unroll
    for (int u = 0; u < 7; ++u) {
      const float* svr = &sv[(ty + 2 * u) * 148 + x0];  // cols x0 .. x0+19
      float vw[20];
      #pragma unroll
      for (int k = 0; k < 20; ++k) vw[k] = svr[k];
      #pragma unroll
      for (int vv = 0; vv < 7; ++vv)
        #pragma unroll
        for (int j = 0; j < 8; ++j)
          acc[j] += W[u * 7 + vv] * vw[j + 2 * vv];
    }
    union { ushort_t u[8]; uint4 v; } pk;
    #pragma unroll
    for (int j = 0; j < 8; ++j) pk.u[j] = f2b(acc[j]);
    bf16* d5p = d5 + ((long)b * 64 + c) * 16384;
    *(uint4*)(d5p + y * 128 + x0) = pk.v;
  }
}

// ---------------------------------------------------------------------------
// K4: fused finale via bf16 MFMA. Residual x prefetched into 32 VGPRs at
// kernel start so its HBM latency hides under staging + MFMA + gating
// (was: 33KB/block fp32 read fully exposed in the tail phase).
// LDS map (53248 B, 3 blocks/CU):
//   [0,18432)      A3 [64px][72], A5 [64px][72]   (MFMA-A staging; dead after conv)
//   [0,17408)      gA [64px][136]                  (overlay after sync)
//   [18432,27136)  X3 [64ch][68px]
//   [27136,35840)  X5 [64ch][68px]
//   [35840,53248)  XH [128ch][68px]                (xh lo/hi halves)
//   [18432,53248)  outL [128oc][68px] f32          (overlay after gating)
// ---------------------------------------------------------------------------
__global__ __launch_bounds__(256) void final_mfma(
    const ushort_t* __restrict__ h, const ushort_t* __restrict__ d3,
    const ushort_t* __restrict__ x3o, const ushort_t* __restrict__ d5,
    const ushort_t* __restrict__ x5o,
    const ushort_t* __restrict__ w4p, const float* __restrict__ b4,
    const ushort_t* __restrict__ w5p, const float* __restrict__ b5,
    const ushort_t* __restrict__ plwp, const float* __restrict__ plb,
    const float* __restrict__ scale, const float* __restrict__ x,
    float* __restrict__ out)
{
  __shared__ __attribute__((aligned(16))) unsigned char sm[53248];
  ushort_t* A3 = (ushort_t*)sm;             // [64 px][72]
  ushort_t* A5 = (ushort_t*)(sm + 9216);    // [64 px][72]
  ushort_t* gA = (ushort_t*)sm;             // [64 px][136] (overlay)
  ushort_t* X3 = (ushort_t*)(sm + 18432);   // [64 ch][68]
  ushort_t* X5 = (ushort_t*)(sm + 27136);   // [64 ch][68]
  ushort_t* XH = (ushort_t*)(sm + 35840);   // [128 ch][68]
  float* outL  = (float*)(sm + 18432);      // [128 oc][68] (overlay)

  const int tid = threadIdx.x;
  const int g0 = blockIdx.x * 64;
  const int b = g0 >> 14, hw0 = g0 & 16383;
  const long base64 = (long)b * 64 * 16384 + hw0;
  const long base256 = (long)b * 256 * 16384 + hw0;
  const int p = tid & 63;

  // ---- prefetch residual x into registers FIRST (deepest-latency stream;
  //      consumed only in the epilogue, so it overlaps the entire kernel)
  float xreg[32];
  {
    const float* xp = x + (long)b * 128 * 16384 + hw0 + p;
    #pragma unroll
    for (int i = 0; i < 32; ++i)
      xreg[i] = xp[(long)((tid >> 6) + 4 * i) * 16384];
  }

  // ---- stage d3/d5 into MFMA-A layout (coalesced 128B/wave-instr)
  #pragma unroll
  for (int i = 0; i < 16; ++i) {
    int ch = (tid >> 6) + 4 * i;
    A3[p * 72 + ch] = d3[base64 + (long)ch * 16384 + p];
    A5[p * 72 + ch] = d5[base64 + (long)ch * 16384 + p];
  }
  // ---- stage x3o/x5o/xh ch-major (coalesced 256B/wave-instr, 2px/lane)
  {
    const int p2 = (tid & 31) * 2, cg8 = tid >> 5;
    #pragma unroll
    for (int i = 0; i < 8; ++i) {
      int ch = cg8 + 8 * i;
      *(unsigned*)&X3[ch * 68 + p2] = *(const unsigned*)&x3o[base64 + (long)ch * 16384 + p2];
      *(unsigned*)&X5[ch * 68 + p2] = *(const unsigned*)&x5o[base64 + (long)ch * 16384 + p2];
    }
    #pragma unroll
    for (int i = 0; i < 16; ++i) {
      int ch = cg8 + 8 * i;
      *(unsigned*)&XH[ch * 68 + p2] = *(const unsigned*)&h[base256 + (long)(128 + ch) * 16384 + p2];
    }
  }
  __syncthreads();

  const int l = tid & 63, lm = l & 15, q = l >> 4;
  const int wv = __builtin_amdgcn_readfirstlane(tid >> 6);

  f32x4 ac1[4], ac2[4];
  #pragma unroll
  for (int n = 0; n < 4; ++n) { ac1[n] = {0.f,0.f,0.f,0.f}; ac2[n] = {0.f,0.f,0.f,0.f}; }
  #pragma unroll
  for (int kc = 0; kc < 2; ++kc) {
    bf16x8 a3f = *(const bf16x8*)&A3[(wv * 16 + lm) * 72 + kc * 32 + q * 8];
    bf16x8 a5f = *(const bf16x8*)&A5[(wv * 16 + lm) * 72 + kc * 32 + q * 8];
    #pragma unroll
    for (int nt = 0; nt < 4; ++nt) {
      bf16x8 bw4 = *(const bf16x8*)&w4p[((nt * 2 + kc) * 64 + l) * 8];
      bf16x8 bw5 = *(const bf16x8*)&w5p[((nt * 2 + kc) * 64 + l) * 8];
      ac1[nt] = MFMA16(a3f, bw4, ac1[nt]);
      ac2[nt] = MFMA16(a5f, bw5, ac2[nt]);
    }
  }
  __syncthreads();  // A3/A5 dead -> gA may overlay

  // gating: attn = (conv + bias) * xNo ; g = xh * attn -> gA in A-layout
  {
    const int pxb = wv * 16 + q * 4;
    #pragma unroll
    for (int nt = 0; nt < 4; ++nt) {
      int oc = nt * 16 + lm;
      float bb1 = b4[oc], bb2 = b5[oc];
      u16x4 x3v = *(const u16x4*)&X3[oc * 68 + pxb];
      u16x4 x5v = *(const u16x4*)&X5[oc * 68 + pxb];
      u16x4 h1v = *(const u16x4*)&XH[oc * 68 + pxb];
      u16x4 h2v = *(const u16x4*)&XH[(64 + oc) * 68 + pxb];
      #pragma unroll
      for (int r = 0; r < 4; ++r) {
        float at1 = (ac1[nt][r] + bb1) * b2f(x3v[r]);
        float at2 = (ac2[nt][r] + bb2) * b2f(x5v[r]);
        float g1 = b2f(h1v[r]) * at1;
        float g2 = b2f(h2v[r]) * at2;
        gA[(pxb + r) * 136 + oc]      = f2b(g1);
        gA[(pxb + r) * 136 + 64 + oc] = f2b(g2);
      }
    }
  }
  __syncthreads();

  f32x4 ap[4][2];
  #pragma unroll
  for (int mt = 0; mt < 4; ++mt) { ap[mt][0] = {0.f,0.f,0.f,0.f}; ap[mt][1] = {0.f,0.f,0.f,0.f}; }
  #pragma unroll
  for (int kc = 0; kc < 4; ++kc) {
    bf16x8 af[4];
    #pragma unroll
    for (int mt = 0; mt < 4; ++mt)
      af[mt] = *(const bf16x8*)&gA[(mt * 16 + lm) * 136 + kc * 32 + q * 8];
    #pragma unroll
    for (int j = 0; j < 2; ++j) {
      bf16x8 bp = *(const bf16x8*)&plwp[(((wv * 2 + j) * 4 + kc) * 64 + l) * 8];
      #pragma unroll
      for (int mt = 0; mt < 4; ++mt)
        ap[mt][j] = MFMA16(af[mt], bp, ap[mt][j]);
    }
  }
  // X3/X5/XH dead (last read before the pre-MFMA barrier) -> outL may overlay
  #pragma unroll
  for (int j = 0; j < 2; ++j) {
    int oc = (wv * 2 + j) * 16 + lm;
    float sc = scale[oc], bb = plb[oc];
    #pragma unroll
    for (int mt = 0; mt < 4; ++mt) {
      int px0 = mt * 16 + q * 4;
      f32x4 vv;
      #pragma unroll
      for (int r = 0; r < 4; ++r) vv[r] = (ap[mt][j][r] + bb) * sc;
      *(f32x4*)&outL[oc * 68 + px0] = vv;
    }
  }
  __syncthreads();
  {
    float* op = out + (long)b * 128 * 16384 + hw0 + p;
    #pragma unroll
    for (int i = 0; i < 32; ++i) {
      int oc = (tid >> 6) + 4 * i;
      op[(long)oc * 16384] = outL[oc * 68 + p] + xreg[i];
    }
  }
}

// ---------------------------------------------------------------------------
extern "C" void kernel_launch(void* const* d_in, const int* in_sizes, int n_in,
                              void* d_out, int out_size, void* d_ws, size_t ws_size,
                              hipStream_t stream)
{
  (void)in_sizes; (void)n_in; (void)out_size; (void)ws_size;
  const float* x       = (const float*)d_in[0];
  const float* ln_w    = (const float*)d_in[1];
  const float* ln_b    = (const float*)d_in[2];
  const float* scale   = (const float*)d_in[3];
  const float* pf_w    = (const float*)d_in[4];
  const float* pf_b    = (const float*)d_in[5];
  const float* lka3_w1 = (const float*)d_in[6];
  const float* lka3_b1 = (const float*)d_in[7];
  const float* lka3_w2 = (const float*)d_in[8];
  const float* lka3_b2 = (const float*)d_in[9];
  const float* lka3_w3 = (const float*)d_in[10];
  const float* lka3_b3 = (const float*)d_in[11];
  const float* lka3_w4 = (const float*)d_in[12];
  const float* lka3_b4 = (const float*)d_in[13];
  const float* lka5_w1 = (const float*)d_in[14];
  const float* lka5_b1 = (const float*)d_in[15];
  const float* lka5_w2 = (const float*)d_in[16];
  const float* lka5_b2 = (const float*)d_in[17];
  const float* lka5_w3 = (const float*)d_in[18];
  const float* lka5_b3 = (const float*)d_in[19];
  const float* x3a_w   = (const float*)d_in[20];
  const float* x3a_b   = (const float*)d_in[21];
  const float* x3b_w   = (const float*)d_in[22];
  const float* x3b_b   = (const float*)d_in[23];
  const float* x5_w    = (const float*)d_in[24];
  const float* x5_b    = (const float*)d_in[25];
  const float* pl_w    = (const float*)d_in[26];
  const float* pl_b    = (const float*)d_in[27];
  float* out = (float*)d_out;

  // ws layout (bf16): h (67,108,864 el) | d3 | x3o | d5 | x5o (16,777,216 el each)
  bf16* h   = (bf16*)d_ws;
  bf16* d3  = h + 67108864L;
  bf16* x3o = d3 + 16777216L;
  bf16* d5  = x3o + 16777216L;
  bf16* x5o = d5 + 16777216L;
  // packed weights:
  //  - pf_wp lives in d_out (free until final_mfma overwrites it)
  //  - w4p/w5p/plwp live in the a1 region of h (dead after dw kernels;
  //    packed after the dw launches, before final)
  ushort_t* pf_wp = (ushort_t*)d_out;
  ushort_t* wsmall = (ushort_t*)d_ws;   // w4p @0, w5p @4096, plwp @8192 (elements)

  dim3 blk(256);

  prepack_pf<<<128, blk, 0, stream>>>(pf_w, pf_wp);
  ln_pf_mfma<<<4096, blk, 0, stream>>>(x, ln_w, ln_b, pf_wp, pf_b, (ushort_t*)h);

  dw_branch1_kernel<<<8192, blk, 0, stream>>>(
      h, lka3_w1, lka3_b1, lka3_w2, lka3_b2, lka3_w3, lka3_b3,
      x3a_w, x3a_b, x3b_w, x3b_b, d3, x3o);

  dw_branch2_kernel<<<8192, blk, 0, stream>>>(
      h, lka5_w1, lka5_b1, lka5_w2, lka5_b2, x5_w, x5_b, d5, x5o);

  prepack_small<<<96, blk, 0, stream>>>(lka3_w4, lka5_w3, pl_w, wsmall);

  final_mfma<<<4096, blk, 0, stream>>>(
      (const ushort_t*)h, (const ushort_t*)d3, (const ushort_t*)x3o,
      (const ushort_t*)d5, (const ushort_t*)x5o,
      wsmall, lka3_b4, wsmall + 4096, lka5_b3,
      wsmall + 8192, pl_b, scale, x, out);
}

// Round 6
// 519.510 us; speedup vs baseline: 1.2407x; 1.2407x over previous
//
#include <hip/hip_runtime.h>
#include <hip/hip_bf16.h>

typedef __hip_bfloat16 bf16;
typedef unsigned short ushort_t;
typedef float f32x4 __attribute__((ext_vector_type(4)));
typedef short bf16x8 __attribute__((ext_vector_type(8)));
typedef ushort_t u16x4 __attribute__((ext_vector_type(4)));

#define MFMA16(a, b, c) __builtin_amdgcn_mfma_f32_16x16x32_bf16(a, b, c, 0, 0, 0)

__device__ inline ushort_t f2b(float f) {
  bf16 h = __float2bfloat16(f);
  return __builtin_bit_cast(ushort_t, h);
}
__device__ inline float b2f(ushort_t u) {
  bf16 h = __builtin_bit_cast(bf16, u);
  return __bfloat162float(h);
}
// bf16 pair unpack (bf16 -> f32 is a 16-bit shift)
__device__ inline float blo(unsigned d) { return __builtin_bit_cast(float, d << 16); }
__device__ inline float bhi(unsigned d) { return __builtin_bit_cast(float, d & 0xffff0000u); }

// Geometry: B=16, C=128, H=W=128, HW=16384, S1=S2=64
// h buffer (bf16) layout: (B, 256, HW); ch 0..63 = a1, 64..127 = a2, 128..255 = xh
// MFMA frag layouts (16x16x32 bf16, m89/m91-verified):
//   A: lane l holds A[m = l&15][k = (l>>4)*8 + j], j=0..7
//   B: lane l holds W[n = l&15][k = (l>>4)*8 + j]  (B^T-input convention)
//   D: lane l reg r holds D[m = (l>>4)*4 + r][n = l&15]

// ---------------------------------------------------------------------------
// Weight pre-pack kernels (bf16, B-fragment order).
// ---------------------------------------------------------------------------
__global__ __launch_bounds__(256) void prepack_pf(
    const float* __restrict__ pf_w, ushort_t* __restrict__ pf_wp)
{
  int idx = blockIdx.x * 256 + threadIdx.x;  // 32768 = 16 tiles * 4 kc * 64 * 8
  int j = idx & 7, lane = (idx >> 3) & 63, kc = (idx >> 9) & 3, t = idx >> 11;
  int oc = t * 16 + (lane & 15), ic = kc * 32 + (lane >> 4) * 8 + j;
  pf_wp[idx] = f2b(pf_w[oc * 128 + ic]);
}

__global__ __launch_bounds__(256) void prepack_small(
    const float* __restrict__ w4, const float* __restrict__ w5,
    const float* __restrict__ plw, ushort_t* __restrict__ dst)
{
  int idx = blockIdx.x * 256 + threadIdx.x;  // 24576: [0,4096) w4p, [4096,8192) w5p, rest plwp
  if (idx < 8192) {
    const float* src = (idx < 4096) ? w4 : w5;
    int k = idx & 4095;
    int j = k & 7, lane = (k >> 3) & 63, kc = (k >> 9) & 1, t = k >> 10;
    int oc = t * 16 + (lane & 15), ic = kc * 32 + (lane >> 4) * 8 + j;
    dst[idx] = f2b(src[oc * 64 + ic]);
  } else {
    int k = idx - 8192;  // 16384 = 8 tiles * 4 kc * 64 * 8
    int j = k & 7, lane = (k >> 3) & 63, kc = (k >> 9) & 3, t = k >> 11;
    int oc = t * 16 + (lane & 15), ic = kc * 32 + (lane >> 4) * 8 + j;
    dst[idx] = f2b(plw[oc * 128 + ic]);
  }
}

// ---------------------------------------------------------------------------
// K1: fused LayerNorm + pointwise 128->256 via bf16 MFMA. Block = 64 px.
// ---------------------------------------------------------------------------
__global__ __launch_bounds__(256) void ln_pf_mfma(
    const float* __restrict__ x, const float* __restrict__ ln_w,
    const float* __restrict__ ln_b, const ushort_t* __restrict__ pf_wp,
    const float* __restrict__ pf_b, ushort_t* __restrict__ h)
{
  __shared__ __attribute__((aligned(16))) unsigned char sm[34816];
  ushort_t* xs = (ushort_t*)sm;             // [64 px][136] bf16 (A-layout, pad 8)
  float* red = (float*)(sm + 17408);        // partial sums [2][4][64]
  float* mrs = (float*)(sm + 17408 + 2048); // mean[64], rstd[64]

  const int tid = threadIdx.x;
  const int p = tid & 63, cg = tid >> 6;
  const int g0 = blockIdx.x * 64;
  const int b = g0 >> 14, hw0 = g0 & 16383;
  const float* xp = x + (long)b * (128L * 16384) + hw0 + p;

  float v[32];
  #pragma unroll
  for (int i = 0; i < 32; ++i) v[i] = xp[(long)(cg * 32 + i) * 16384];
  float s = 0.f, ss = 0.f;
  #pragma unroll
  for (int i = 0; i < 32; ++i) { s += v[i]; ss += v[i] * v[i]; }
  red[cg * 64 + p] = s;
  red[256 + cg * 64 + p] = ss;
  __syncthreads();
  if (tid < 64) {
    float st = red[tid] + red[64 + tid] + red[128 + tid] + red[192 + tid];
    float sst = red[256 + tid] + red[320 + tid] + red[384 + tid] + red[448 + tid];
    float m = st * 0.0078125f;
    float var = sst * 0.0078125f - m * m;
    mrs[tid] = m;
    mrs[64 + tid] = rsqrtf(var + 1e-6f);
  }
  __syncthreads();
  {
    float m = mrs[p], rs = mrs[64 + p];
    #pragma unroll
    for (int i = 0; i < 32; ++i) {
      int c = cg * 32 + i;
      xs[p * 136 + c] = f2b((v[i] - m) * rs * ln_w[c] + ln_b[c]);
    }
  }
  __syncthreads();

  const int l = tid & 63, lm = l & 15, q = l >> 4;
  const int wv = __builtin_amdgcn_readfirstlane(tid >> 6);
  f32x4 acc[4][4];
  #pragma unroll
  for (int a = 0; a < 4; ++a)
    #pragma unroll
    for (int n = 0; n < 4; ++n) acc[a][n] = {0.f, 0.f, 0.f, 0.f};

  #pragma unroll
  for (int kc = 0; kc < 4; ++kc) {
    bf16x8 af[4], bfr[4];
    #pragma unroll
    for (int mt = 0; mt < 4; ++mt)
      af[mt] = *(const bf16x8*)&xs[(mt * 16 + lm) * 136 + kc * 32 + q * 8];
    #pragma unroll
    for (int nt = 0; nt < 4; ++nt)
      bfr[nt] = *(const bf16x8*)&pf_wp[(((wv * 4 + nt) * 4 + kc) * 64 + l) * 8];
    #pragma unroll
    for (int mt = 0; mt < 4; ++mt)
      #pragma unroll
      for (int nt = 0; nt < 4; ++nt)
        acc[mt][nt] = MFMA16(af[mt], bfr[nt], acc[mt][nt]);
  }
  __syncthreads();

  // epilogue: + bias, transpose via LDS to [oc][px], then coalesced store
  ushort_t* hst = (ushort_t*)sm;  // [256 oc][68 px] bf16
  #pragma unroll
  for (int nt = 0; nt < 4; ++nt) {
    int oc = wv * 64 + nt * 16 + lm;
    float bias = pf_b[oc];
    #pragma unroll
    for (int mt = 0; mt < 4; ++mt) {
      int px0 = mt * 16 + q * 4;
      union { ushort_t u[4]; uint2 w; } pk;
      #pragma unroll
      for (int r = 0; r < 4; ++r) pk.u[r] = f2b(acc[mt][nt][r] + bias);
      *(uint2*)&hst[oc * 68 + px0] = pk.w;
    }
  }
  __syncthreads();
  {
    int px = (tid & 31) * 2;
    int ocb = tid >> 5;
    ushort_t* hp = h + (long)b * 256 * 16384 + hw0 + px;
    #pragma unroll
    for (int i = 0; i < 32; ++i) {
      int oc = ocb + 8 * i;
      *(unsigned*)(hp + (long)oc * 16384) = *(unsigned*)&hst[oc * 68 + px];
    }
  }
}

// ---------------------------------------------------------------------------
// Fused branch-1 depthwise chain (validated round 3).
// ---------------------------------------------------------------------------
__global__ __launch_bounds__(256) void dw_branch1_kernel(
    const bf16* __restrict__ hbuf,
    const float* __restrict__ w1, const float* __restrict__ b1,
    const float* __restrict__ w2, const float* __restrict__ b2,
    const float* __restrict__ w3, const float* __restrict__ b3,
    const float* __restrict__ wa, const float* __restrict__ ba,
    const float* __restrict__ wb, const float* __restrict__ bb,
    bf16* __restrict__ d3, bf16* __restrict__ x3o)
{
  __shared__ __attribute__((aligned(16))) unsigned char smem[28000];
  float* st1 = (float*)smem;                 // 26*140*4 = 14560 B
  float* st2 = (float*)(smem + 14560);       // 24*140*4 = 13440 B (post-sync)
  ushort_t* sa = (ushort_t*)(smem + 14560);  // 26*160*2 =  8320 B (pre-sync, overlays st2)
  unsigned* sad = (unsigned*)sa;

  const int t = blockIdx.x;
  const int band = t & 7, c = (t >> 3) & 63, b = t >> 9;
  const int y0 = band * 16;
  const int tid = threadIdx.x;
  const bf16* ap = hbuf + ((long)b * 256 + c) * 16384;

  // ---- zero pad columns (dwords 0..3 = cols 0..7, 68..79 = cols 136..159)
  for (int i = tid; i < 26 * 16; i += 256) {
    int r = i >> 4, j = i & 15;
    int dw = (j < 4) ? j : (64 + j);
    sad[r * 80 + dw] = 0u;
  }
  // ---- load 26 rows (gy = y0-5 .. y0+20), 128 cols as 64 dwords, coalesced
  {
    const int lane = tid & 63, w = tid >> 6;
    #pragma unroll
    for (int i = 0; i < 7; ++i) {
      int rr = w + 4 * i;
      if (rr < 26) {
        int gy = y0 - 5 + rr;
        unsigned val = 0u;
        if ((unsigned)gy < 128u) val = *(const unsigned*)(ap + gy * 128 + lane * 2);
        sad[rr * 80 + 4 + lane] = val;
      }
    }
  }
  __syncthreads();

  // ---- stage B: st1 = conv1x3 horiz (w1), 26 rows x 136 cols, 8-col tasks
  {
    float W0 = w1[c * 3], Wm = w1[c * 3 + 1], Wp = w1[c * 3 + 2];
    const float B1v = b1[c];
    for (int task = tid; task < 26 * 17; task += 256) {
      int r = task / 17, g = task - r * 17;
      int c0 = g * 8;  // st1 cols c0..c0+7, x = c0-4..c0+3
      const unsigned* sr = sad + r * 80 + (c0 >> 1) + 1;
      unsigned e0 = sr[0], e1 = sr[1], e2 = sr[2], e3 = sr[3], e4 = sr[4], e5 = sr[5];
      float vw[12];
      vw[0] = blo(e0); vw[1] = bhi(e0); vw[2] = blo(e1); vw[3] = bhi(e1);
      vw[4] = blo(e2); vw[5] = bhi(e2); vw[6] = blo(e3); vw[7] = bhi(e3);
      vw[8] = blo(e4); vw[9] = bhi(e4); vw[10] = blo(e5); vw[11] = bhi(e5);
      int gy = y0 - 5 + r;
      bool rok = (unsigned)gy < 128u;
      float* dst = &st1[r * 140 + c0];
      #pragma unroll
      for (int j = 0; j < 8; ++j) {
        float v = W0 * vw[j + 1] + Wm * vw[j + 2] + Wp * vw[j + 3] + B1v;
        int xx = c0 - 4 + j;
        dst[j] = (rok && (unsigned)xx < 128u) ? v : 0.f;
      }
    }
  }

  // thread -> output strip mapping: 16 col-groups x 16 rows
  const int tx = tid & 15, ty = tid >> 4;
  const int x0 = tx * 8;
  const int y = y0 + ty;

  // ---- stage E: x3o = (3x1 vert wb) o (1x3 horiz wa), direct from sa registers
  {
    float A0 = wa[c * 3], A1 = wa[c * 3 + 1], A2 = wa[c * 3 + 2];
    float Bv0 = wb[c * 3], Bv1 = wb[c * 3 + 1], Bv2 = wb[c * 3 + 2];
    const float BAv = ba[c], BBv = bb[c];
    float su[3][8];
    #pragma unroll
    for (int dy = 0; dy < 3; ++dy) {
      int gy2 = y - 1 + dy;
      int srow = ty + 4 + dy;  // gy2 - (y0-5)
      const unsigned* sr = sad + srow * 80 + (x0 >> 1) + 3;  // cols x0+6..x0+17
      unsigned e0 = sr[0], e1 = sr[1], e2 = sr[2], e3 = sr[3], e4 = sr[4], e5 = sr[5];
      float vw[12];
      vw[0] = blo(e0); vw[1] = bhi(e0); vw[2] = blo(e1); vw[3] = bhi(e1);
      vw[4] = blo(e2); vw[5] = bhi(e2); vw[6] = blo(e3); vw[7] = bhi(e3);
      vw[8] = blo(e4); vw[9] = bhi(e4); vw[10] = blo(e5); vw[11] = bhi(e5);
      bool rok = (unsigned)gy2 < 128u;
      #pragma unroll
      for (int j = 0; j < 8; ++j) {
        float v = A0 * vw[j + 1] + A1 * vw[j + 2] + A2 * vw[j + 3] + BAv;
        su[dy][j] = rok ? v : 0.f;
      }
    }
    union { ushort_t u[8]; uint4 v; } pk;
    #pragma unroll
    for (int j = 0; j < 8; ++j)
      pk.u[j] = f2b(Bv0 * su[0][j] + Bv1 * su[1][j] + Bv2 * su[2][j] + BBv);
    bf16* x3p = x3o + ((long)b * 64 + c) * 16384;
    *(uint4*)(x3p + y * 128 + x0) = pk.v;
  }
  __syncthreads();  // sa dead from here; st2 may overwrite its space

  // ---- stage C: st2 = conv3x1 vert (w2) over st1, 24 rows x 136 cols
  {
    float W0 = w2[c * 3], Wm = w2[c * 3 + 1], Wp = w2[c * 3 + 2];
    const float B2v = b2[c];
    for (int task = tid; task < 24 * 17; task += 256) {
      int q = task / 17, g = task - q * 17;
      int c0 = g * 8;
      const float* r0 = &st1[q * 140 + c0];
      const float* r1 = &st1[(q + 1) * 140 + c0];
      const float* r2 = &st1[(q + 2) * 140 + c0];
      int gy = y0 - 4 + q;
      bool rok = (unsigned)gy < 128u;
      float* dst = &st2[q * 140 + c0];
      #pragma unroll
      for (int j = 0; j < 8; ++j) {
        float v = W0 * r0[j] + Wm * r1[j] + Wp * r2[j] + B2v;
        int xx = c0 - 4 + j;
        dst[j] = (rok && (unsigned)xx < 128u) ? v : 0.f;
      }
    }
  }
  __syncthreads();

  // ---- stage D: d3 = dilated 5x5 (w3, dil 2) over st2
  {
    float W[25];
    #pragma unroll
    for (int k = 0; k < 25; ++k) W[k] = w3[c * 25 + k];
    float acc[8];
    #pragma unroll
    for (int j = 0; j < 8; ++j) acc[j] = b3[c];
    #pragma unroll
    for (int u = 0; u < 5; ++u) {
      const float* svr = &st2[(ty + 2 * u) * 140 + x0];  // cols x0 .. x0+15
      float vw[16];
      #pragma unroll
      for (int k = 0; k < 16; ++k) vw[k] = svr[k];
      #pragma unroll
      for (int vv = 0; vv < 5; ++vv)
        #pragma unroll
        for (int j = 0; j < 8; ++j)
          acc[j] += W[u * 5 + vv] * vw[j + 2 * vv];
    }
    union { ushort_t u[8]; uint4 v; } pk;
    #pragma unroll
    for (int j = 0; j < 8; ++j) pk.u[j] = f2b(acc[j]);
    bf16* d3p = d3 + ((long)b * 64 + c) * 16384;
    *(uint4*)(d3p + y * 128 + x0) = pk.v;
  }
}

// ---------------------------------------------------------------------------
// Fused branch-2 depthwise chain (validated in round 2).
// ---------------------------------------------------------------------------
__global__ __launch_bounds__(256) void dw_branch2_kernel(
    const bf16* __restrict__ hbuf,
    const float* __restrict__ w1, const float* __restrict__ b1,
    const float* __restrict__ w2, const float* __restrict__ b2,
    const float* __restrict__ w5, const float* __restrict__ b5,
    bf16* __restrict__ d5, bf16* __restrict__ x5o)
{
  __shared__ ushort_t sa[32 * 160];   // 10240 B
  __shared__ float sv[28 * 148];      // 16576 B

  const int t = blockIdx.x;
  const int band = t & 7, c = (t >> 3) & 63, b = t >> 9;
  const int y0 = band * 16;
  const int tid = threadIdx.x;
  const bf16* ap = hbuf + ((long)b * 256 + 64 + c) * 16384;

  // ---- zero the pad columns (dwords 0..3 = cols 0..7, 68..79 = cols 136..159)
  unsigned* sad = (unsigned*)sa;
  for (int i = tid; i < 32 * 16; i += 256) {
    int r = i >> 4, j = i & 15;
    int dw = (j < 4) ? j : (64 + j);
    sad[r * 80 + dw] = 0u;
  }
  // ---- load 32 rows (gy = y0-8 .. y0+23), 128 cols as 64 dwords, coalesced
  {
    const int lane = tid & 63, w = tid >> 6;
    #pragma unroll
    for (int i = 0; i < 8; ++i) {
      int rr = w + 4 * i;
      int gy = y0 - 8 + rr;
      unsigned val = 0u;
      if ((unsigned)gy < 128u) val = *(const unsigned*)(ap + gy * 128 + lane * 2);
      sad[rr * 80 + 4 + lane] = val;
    }
  }
  __syncthreads();

  // ---- stage 1: sv = conv5x5(sa) (w1), 28 rows x 144 cols, 8-col tasks
  {
    float W[25];
    #pragma unroll
    for (int k = 0; k < 25; ++k) W[k] = w1[c * 25 + k];
    const float B1v = b1[c];
    for (int task = tid; task < 28 * 18; task += 256) {
      int r = task / 18, g = task - r * 18;
      int c0 = g * 8;
      float acc[8];
      #pragma unroll
      for (int j = 0; j < 8; ++j) acc[j] = B1v;
      #pragma unroll
      for (int u = 0; u < 5; ++u) {
        const unsigned* sr = sad + (r + u) * 80 + (c0 >> 1);
        unsigned e0 = sr[0], e1 = sr[1], e2 = sr[2], e3 = sr[3], e4 = sr[4], e5 = sr[5];
        float vw[12];
        vw[0] = blo(e0); vw[1] = bhi(e0); vw[2] = blo(e1); vw[3] = bhi(e1);
        vw[4] = blo(e2); vw[5] = bhi(e2); vw[6] = blo(e3); vw[7] = bhi(e3);
        vw[8] = blo(e4); vw[9] = bhi(e4); vw[10] = blo(e5); vw[11] = bhi(e5);
        #pragma unroll
        for (int v5 = 0; v5 < 5; ++v5)
          #pragma unroll
          for (int j = 0; j < 8; ++j)
            acc[j] += W[u * 5 + v5] * vw[j + v5];
      }
      int gy = y0 - 6 + r;
      bool rok = (unsigned)gy < 128u;
      float* svr = &sv[r * 148 + c0];
      #pragma unroll
      for (int j = 0; j < 8; ++j) {
        int xx = c0 + j - 6;
        svr[j] = (rok && (unsigned)xx < 128u) ? acc[j] : 0.f;
      }
    }
  }

  // thread -> output mapping for stages 2/3: 16 col-groups x 16 rows
  const int tx = tid & 15, ty = tid >> 4;
  const int x0 = tx * 8;
  const int y = y0 + ty;

  // ---- stage 2: x5o = conv5x5(sa) (w5) at output rows (reads sa only)
  {
    float W[25];
    #pragma unroll
    for (int k = 0; k < 25; ++k) W[k] = w5[c * 25 + k];
    float acc[8];
    #pragma unroll
    for (int j = 0; j < 8; ++j) acc[j] = b5[c];
    #pragma unroll
    for (int u = 0; u < 5; ++u) {
      const unsigned* sr = sad + (ty + 6 + u) * 80 + (x0 >> 1);
      unsigned e0 = sr[3], e1 = sr[4], e2 = sr[5], e3 = sr[6], e4 = sr[7], e5 = sr[8];
      float vw[12];  // sa cols x0+6 .. x0+17
      vw[0] = blo(e0); vw[1] = bhi(e0); vw[2] = blo(e1); vw[3] = bhi(e1);
      vw[4] = blo(e2); vw[5] = bhi(e2); vw[6] = blo(e3); vw[7] = bhi(e3);
      vw[8] = blo(e4); vw[9] = bhi(e4); vw[10] = blo(e5); vw[11] = bhi(e5);
      #pragma unroll
      for (int v5 = 0; v5 < 5; ++v5)
        #pragma unroll
        for (int j = 0; j < 8; ++j)
          acc[j] += W[u * 5 + v5] * vw[j + v5];
    }
    union { ushort_t u[8]; uint4 v; } pk;
    #pragma unroll
    for (int j = 0; j < 8; ++j) pk.u[j] = f2b(acc[j]);
    bf16* x5p = x5o + ((long)b * 64 + c) * 16384;
    *(uint4*)(x5p + y * 128 + x0) = pk.v;
  }
  __syncthreads();

  // ---- stage 3: d5 = dilated 7x7 (w2, dil 2) over sv
  {
    float W[49];
    #pragma unroll
    for (int k = 0; k < 49; ++k) W[k] = w2[c * 49 + k];
    float acc[8];
    #pragma unroll
    for (int j = 0; j < 8; ++j) acc[j] = b2[c];
    #pragma unroll
    for (int u = 0; u < 7; ++u) {
      const float* svr = &sv[(ty + 2 * u) * 148 + x0];  // cols x0 .. x0+19
      float vw[20];
      #pragma unroll
      for (int k = 0; k < 20; ++k) vw[k] = svr[k];
      #pragma unroll
      for (int vv = 0; vv < 7; ++vv)
        #pragma unroll
        for (int j = 0; j < 8; ++j)
          acc[j] += W[u * 7 + vv] * vw[j + 2 * vv];
    }
    union { ushort_t u[8]; uint4 v; } pk;
    #pragma unroll
    for (int j = 0; j < 8; ++j) pk.u[j] = f2b(acc[j]);
    bf16* d5p = d5 + ((long)b * 64 + c) * 16384;
    *(uint4*)(d5p + y * 128 + x0) = pk.v;
  }
}

// ---------------------------------------------------------------------------
// K4: fused finale via bf16 MFMA (R4 structure).
// Round-6 deltas: (1) A3/A5 staged as ch-pair uint writes (half the LDS ops,
// half the 8-way write conflicts); (2) XH reg-staged async: loads issued at
// kernel top, LDS write deferred to after MFMA1, fenced by the EXISTING
// post-MFMA1 barrier (short 16-VGPR live range — NOT the kernel-long
// prefetch that spilled in R5).
// LDS map (53248 B, 3 blocks/CU):
//   [0,18432)      A3 [64px][72], A5 [64px][72]   (MFMA-A staging; dead after conv)
//   [0,17408)      gA [64px][136]                  (overlay after sync)
//   [18432,27136)  X3 [64ch][68px]
//   [27136,35840)  X5 [64ch][68px]
//   [35840,53248)  XH [128ch][68px]                (xh lo/hi halves)
//   [18432,53248)  outL [128oc][68px] f32          (overlay after gating)
// ---------------------------------------------------------------------------
__global__ __launch_bounds__(256) void final_mfma(
    const ushort_t* __restrict__ h, const ushort_t* __restrict__ d3,
    const ushort_t* __restrict__ x3o, const ushort_t* __restrict__ d5,
    const ushort_t* __restrict__ x5o,
    const ushort_t* __restrict__ w4p, const float* __restrict__ b4,
    const ushort_t* __restrict__ w5p, const float* __restrict__ b5,
    const ushort_t* __restrict__ plwp, const float* __restrict__ plb,
    const float* __restrict__ scale, const float* __restrict__ x,
    float* __restrict__ out)
{
  __shared__ __attribute__((aligned(16))) unsigned char sm[53248];
  ushort_t* A3 = (ushort_t*)sm;             // [64 px][72]
  ushort_t* A5 = (ushort_t*)(sm + 9216);    // [64 px][72]
  ushort_t* gA = (ushort_t*)sm;             // [64 px][136] (overlay)
  ushort_t* X3 = (ushort_t*)(sm + 18432);   // [64 ch][68]
  ushort_t* X5 = (ushort_t*)(sm + 27136);   // [64 ch][68]
  ushort_t* XH = (ushort_t*)(sm + 35840);   // [128 ch][68]
  float* outL  = (float*)(sm + 18432);      // [128 oc][68] (overlay)

  const int tid = threadIdx.x;
  const int g0 = blockIdx.x * 64;
  const int b = g0 >> 14, hw0 = g0 & 16383;
  const long base64 = (long)b * 64 * 16384 + hw0;
  const long base256 = (long)b * 256 * 16384 + hw0;
  const int p = tid & 63;
  const int p2 = (tid & 31) * 2, cg8 = tid >> 5;

  // ---- issue XH loads into registers first (largest staging stream; LDS
  //      write deferred to after MFMA1 so HBM latency hides under staging+conv)
  unsigned xhreg[16];
  #pragma unroll
  for (int i = 0; i < 16; ++i) {
    int ch = cg8 + 8 * i;
    xhreg[i] = *(const unsigned*)&h[base256 + (long)(128 + ch) * 16384 + p2];
  }

  // ---- stage d3/d5 into MFMA-A layout, ch-pairs packed as uint
  //      (coalesced global loads; 8 uint LDS writes per buffer per thread)
  #pragma unroll
  for (int i = 0; i < 8; ++i) {
    int ch = (tid >> 6) * 2 + 8 * i;
    unsigned v3 = (unsigned)d3[base64 + (long)ch * 16384 + p] |
                  ((unsigned)d3[base64 + (long)(ch + 1) * 16384 + p] << 16);
    unsigned v5 = (unsigned)d5[base64 + (long)ch * 16384 + p] |
                  ((unsigned)d5[base64 + (long)(ch + 1) * 16384 + p] << 16);
    *(unsigned*)&A3[p * 72 + ch] = v3;
    *(unsigned*)&A5[p * 72 + ch] = v5;
  }
  // ---- stage x3o/x5o ch-major (coalesced 256B/wave-instr, 2px/lane)
  #pragma unroll
  for (int i = 0; i < 8; ++i) {
    int ch = cg8 + 8 * i;
    *(unsigned*)&X3[ch * 68 + p2] = *(const unsigned*)&x3o[base64 + (long)ch * 16384 + p2];
    *(unsigned*)&X5[ch * 68 + p2] = *(const unsigned*)&x5o[base64 + (long)ch * 16384 + p2];
  }
  __syncthreads();

  const int l = tid & 63, lm = l & 15, q = l >> 4;
  const int wv = __builtin_amdgcn_readfirstlane(tid >> 6);

  f32x4 ac1[4], ac2[4];
  #pragma unroll
  for (int n = 0; n < 4; ++n) { ac1[n] = {0.f,0.f,0.f,0.f}; ac2[n] = {0.f,0.f,0.f,0.f}; }
  #pragma unroll
  for (int kc = 0; kc < 2; ++kc) {
    bf16x8 a3f = *(const bf16x8*)&A3[(wv * 16 + lm) * 72 + kc * 32 + q * 8];
    bf16x8 a5f = *(const bf16x8*)&A5[(wv * 16 + lm) * 72 + kc * 32 + q * 8];
    #pragma unroll
    for (int nt = 0; nt < 4; ++nt) {
      bf16x8 bw4 = *(const bf16x8*)&w4p[((nt * 2 + kc) * 64 + l) * 8];
      bf16x8 bw5 = *(const bf16x8*)&w5p[((nt * 2 + kc) * 64 + l) * 8];
      ac1[nt] = MFMA16(a3f, bw4, ac1[nt]);
      ac2[nt] = MFMA16(a5f, bw5, ac2[nt]);
    }
  }

  // ---- deferred XH LDS write (loads long since landed; fenced by the
  //      barrier below, which also retires A3/A5 for the gA overlay)
  #pragma unroll
  for (int i = 0; i < 16; ++i) {
    int ch = cg8 + 8 * i;
    *(unsigned*)&XH[ch * 68 + p2] = xhreg[i];
  }
  __syncthreads();

  // gating: attn = (conv + bias) * xNo ; g = xh * attn -> gA in A-layout
  {
    const int pxb = wv * 16 + q * 4;
    #pragma unroll
    for (int nt = 0; nt < 4; ++nt) {
      int oc = nt * 16 + lm;
      float bb1 = b4[oc], bb2 = b5[oc];
      u16x4 x3v = *(const u16x4*)&X3[oc * 68 + pxb];
      u16x4 x5v = *(const u16x4*)&X5[oc * 68 + pxb];
      u16x4 h1v = *(const u16x4*)&XH[oc * 68 + pxb];
      u16x4 h2v = *(const u16x4*)&XH[(64 + oc) * 68 + pxb];
      #pragma unroll
      for (int r = 0; r < 4; ++r) {
        float at1 = (ac1[nt][r] + bb1) * b2f(x3v[r]);
        float at2 = (ac2[nt][r] + bb2) * b2f(x5v[r]);
        float g1 = b2f(h1v[r]) * at1;
        float g2 = b2f(h2v[r]) * at2;
        gA[(pxb + r) * 136 + oc]      = f2b(g1);
        gA[(pxb + r) * 136 + 64 + oc] = f2b(g2);
      }
    }
  }
  __syncthreads();

  f32x4 ap[4][2];
  #pragma unroll
  for (int mt = 0; mt < 4; ++mt) { ap[mt][0] = {0.f,0.f,0.f,0.f}; ap[mt][1] = {0.f,0.f,0.f,0.f}; }
  #pragma unroll
  for (int kc = 0; kc < 4; ++kc) {
    bf16x8 af[4];
    #pragma unroll
    for (int mt = 0; mt < 4; ++mt)
      af[mt] = *(const bf16x8*)&gA[(mt * 16 + lm) * 136 + kc * 32 + q * 8];
    #pragma unroll
    for (int j = 0; j < 2; ++j) {
      bf16x8 bp = *(const bf16x8*)&plwp[(((wv * 2 + j) * 4 + kc) * 64 + l) * 8];
      #pragma unroll
      for (int mt = 0; mt < 4; ++mt)
        ap[mt][j] = MFMA16(af[mt], bp, ap[mt][j]);
    }
  }
  // X3/X5/XH dead (last read before the pre-MFMA barrier) -> outL may overlay
  #pragma unroll
  for (int j = 0; j < 2; ++j) {
    int oc = (wv * 2 + j) * 16 + lm;
    float sc = scale[oc], bb = plb[oc];
    #pragma unroll
    for (int mt = 0; mt < 4; ++mt) {
      int px0 = mt * 16 + q * 4;
      f32x4 vv;
      #pragma unroll
      for (int r = 0; r < 4; ++r) vv[r] = (ap[mt][j][r] + bb) * sc;
      *(f32x4*)&outL[oc * 68 + px0] = vv;
    }
  }
  __syncthreads();
  {
    const float* xp = x + (long)b * 128 * 16384 + hw0 + p;
    float* op = out + (long)b * 128 * 16384 + hw0 + p;
    #pragma unroll
    for (int i = 0; i < 32; ++i) {
      int oc = (tid >> 6) + 4 * i;
      op[(long)oc * 16384] = outL[oc * 68 + p] + xp[(long)oc * 16384];
    }
  }
}

// ---------------------------------------------------------------------------
extern "C" void kernel_launch(void* const* d_in, const int* in_sizes, int n_in,
                              void* d_out, int out_size, void* d_ws, size_t ws_size,
                              hipStream_t stream)
{
  (void)in_sizes; (void)n_in; (void)out_size; (void)ws_size;
  const float* x       = (const float*)d_in[0];
  const float* ln_w    = (const float*)d_in[1];
  const float* ln_b    = (const float*)d_in[2];
  const float* scale   = (const float*)d_in[3];
  const float* pf_w    = (const float*)d_in[4];
  const float* pf_b    = (const float*)d_in[5];
  const float* lka3_w1 = (const float*)d_in[6];
  const float* lka3_b1 = (const float*)d_in[7];
  const float* lka3_w2 = (const float*)d_in[8];
  const float* lka3_b2 = (const float*)d_in[9];
  const float* lka3_w3 = (const float*)d_in[10];
  const float* lka3_b3 = (const float*)d_in[11];
  const float* lka3_w4 = (const float*)d_in[12];
  const float* lka3_b4 = (const float*)d_in[13];
  const float* lka5_w1 = (const float*)d_in[14];
  const float* lka5_b1 = (const float*)d_in[15];
  const float* lka5_w2 = (const float*)d_in[16];
  const float* lka5_b2 = (const float*)d_in[17];
  const float* lka5_w3 = (const float*)d_in[18];
  const float* lka5_b3 = (const float*)d_in[19];
  const float* x3a_w   = (const float*)d_in[20];
  const float* x3a_b   = (const float*)d_in[21];
  const float* x3b_w   = (const float*)d_in[22];
  const float* x3b_b   = (const float*)d_in[23];
  const float* x5_w    = (const float*)d_in[24];
  const float* x5_b    = (const float*)d_in[25];
  const float* pl_w    = (const float*)d_in[26];
  const float* pl_b    = (const float*)d_in[27];
  float* out = (float*)d_out;

  // ws layout (bf16): h (67,108,864 el) | d3 | x3o | d5 | x5o (16,777,216 el each)
  bf16* h   = (bf16*)d_ws;
  bf16* d3  = h + 67108864L;
  bf16* x3o = d3 + 16777216L;
  bf16* d5  = x3o + 16777216L;
  bf16* x5o = d5 + 16777216L;
  // packed weights:
  //  - pf_wp lives in d_out (free until final_mfma overwrites it)
  //  - w4p/w5p/plwp live in the a1 region of h (dead after dw kernels;
  //    packed after the dw launches, before final)
  ushort_t* pf_wp = (ushort_t*)d_out;
  ushort_t* wsmall = (ushort_t*)d_ws;   // w4p @0, w5p @4096, plwp @8192 (elements)

  dim3 blk(256);

  prepack_pf<<<128, blk, 0, stream>>>(pf_w, pf_wp);
  ln_pf_mfma<<<4096, blk, 0, stream>>>(x, ln_w, ln_b, pf_wp, pf_b, (ushort_t*)h);

  dw_branch1_kernel<<<8192, blk, 0, stream>>>(
      h, lka3_w1, lka3_b1, lka3_w2, lka3_b2, lka3_w3, lka3_b3,
      x3a_w, x3a_b, x3b_w, x3b_b, d3, x3o);

  dw_branch2_kernel<<<8192, blk, 0, stream>>>(
      h, lka5_w1, lka5_b1, lka5_w2, lka5_b2, x5_w, x5_b, d5, x5o);

  prepack_small<<<96, blk, 0, stream>>>(lka3_w4, lka5_w3, pl_w, wsmall);

  final_mfma<<<4096, blk, 0, stream>>>(
      (const ushort_t*)h, (const ushort_t*)d3, (const ushort_t*)x3o,
      (const ushort_t*)d5, (const ushort_t*)x5o,
      wsmall, lka3_b4, wsmall + 4096, lka5_b3,
      wsmall + 8192, pl_b, scale, x, out);
}